// Round 9
// baseline (1057.579 us; speedup 1.0000x reference)
//
#include <hip/hip_runtime.h>
#include <stdint.h>
#include <math.h>

// ---------------- problem constants ----------------
#define N_ROWS   16384
#define N_CODES  8192
#define DIMV     256
#define RT       32
#define CK       32                 // v1 fallback chunk
#define NCHUNK   (N_CODES / CK)
#define CK3      32                 // v11 chunk
#define NIT3     (N_CODES / CK3)    // 256
#define OUT_ZQ_N ((size_t)N_ROWS * DIMV)
#define OUT_LOSS OUT_ZQ_N
#define OUT_CODE (OUT_ZQ_N + 1)

// ---------------- workspace layout ----------------
#define WS_CBHI 0u
#define WS_CBT  4194304u
#define WS_ACC  8388608u
#define WS_NEED (8388608u + 64u)

// ---------------- LDS layout (bytes), v11 ----------------
// Wave-specialized: waves 0-1 = G1 (logits -> ACC), waves 2-3 = G2 (z_q
// MFMA from P), waves 4-7 = C (threefry + softmax + stats + top4 + P).
// SEG1: G1(c) | G2(c-1) | C:threefry(c);  BAR1;
// SEG2: DMA(c+1) + C:float(c)->P;         BAR2.
// VALU (C) and MFMA/LDS (G) overlap by construction instead of phase-
// alternating. 61,952B -> 2 blocks/CU. z kept as persistent bf16 LDS tile
// (frees zhi regs); acc2 (64 VGPR) only on G2 path; C path ~16 regs.
#define ZT_OFF    0          // [32 rows][264 bf16] = 16896 (persistent)
#define ZT_ROW    264
#define CBH0_OFF  16896      // 16 blocks (2 codes x 512B) @1056, dbuf
#define CBH1_OFF  33792
#define CBH_SZ    16896
#define BSTRIDE   1056
#define ACC_OFF   50688      // [32 codes][144B] f32 rows (single buffer)
#define ACC_ROW   144
#define P0_OFF    55296      // [32 rows][80B] bf16, x2
#define P_ROW     80
#define P_BUF_SZ  2560
#define S2B_OFF   60416      // [4 cw][32 rows] f32
#define SKL_OFF   60928
#define TKL_OFF   61440
#define SMEM_BYTES 61952
#define CAND_OFF  16896      // epilogue cand overlays CBH0 (32 rows x 256B)

typedef __attribute__((ext_vector_type(8))) short short8;
typedef __attribute__((ext_vector_type(4))) float float4v;

typedef __attribute__((address_space(1))) uint32_t g_u32;
typedef __attribute__((address_space(3))) uint32_t l_u32;

// async global->LDS DMA, 16B/lane; LDS dest = wave-uniform base + lane*16
__device__ __forceinline__ void dma16(const void* gsrc, void* ldst) {
  __builtin_amdgcn_global_load_lds((g_u32*)gsrc, (l_u32*)ldst, 16, 0, 0);
}

__device__ __forceinline__ uint32_t rotl32(uint32_t x, int r) {
  return __builtin_rotateleft32(x, (uint32_t)r);
}

// Threefry-2x32, key=(0,42), counter=(0, c); out0^out1 (JAX partitionable).
__device__ __forceinline__ uint32_t threefry_bits(uint32_t c) {
  const uint32_t k0 = 0u, k1 = 42u;
  const uint32_t k2 = 0x1BD11BDAu ^ k0 ^ k1;
  uint32_t x0 = 0u + k0;
  uint32_t x1 = c + k1;
#define TF_R(r) { x0 += x1; x1 = rotl32(x1, r); x1 ^= x0; }
  TF_R(13) TF_R(15) TF_R(26) TF_R(6)
  x0 += k1; x1 += k2 + 1u;
  TF_R(17) TF_R(29) TF_R(16) TF_R(24)
  x0 += k2; x1 += k0 + 2u;
  TF_R(13) TF_R(15) TF_R(26) TF_R(6)
  x0 += k0; x1 += k1 + 3u;
  TF_R(17) TF_R(29) TF_R(16) TF_R(24)
  x0 += k1; x1 += k2 + 4u;
  TF_R(13) TF_R(15) TF_R(26) TF_R(6)
  x0 += k2; x1 += k0 + 5u;
#undef TF_R
  return x0 ^ x1;
}

// accurate gumbel for the v1 fallback path
__device__ __forceinline__ float gumbel_at_v1(uint32_t idx) {
  uint32_t bits = threefry_bits(idx);
  float u = __uint_as_float((bits >> 9) | 0x3f800000u) - 1.0f;
  u = fmaxf(u, 1.17549435e-38f);
  return -logf(-logf(u));
}

__device__ __forceinline__ unsigned short f2bf(float x) {
  uint32_t u = __float_as_uint(x);
  u += 0x7fffu + ((u >> 16) & 1u);
  return (unsigned short)(u >> 16);
}
__device__ __forceinline__ float bf2f(unsigned short h) {
  return __uint_as_float(((uint32_t)h) << 16);
}

// order-preserving float->u32 key (larger float => larger key)
__device__ __forceinline__ uint32_t fkey(float x) {
  uint32_t b = __float_as_uint(x);
  return (b & 0x80000000u) ? ~b : (b | 0x80000000u);
}
__device__ __forceinline__ float fkey_inv(uint32_t k) {
  uint32_t b = (k & 0x80000000u) ? (k ^ 0x80000000u) : ~k;
  return __uint_as_float(b);
}

// ================= prep: cb fp32 -> bf16 hi + chunk-blocked transpose =================
__global__ __launch_bounds__(256)
void vq_prep(const float* __restrict__ cb, char* __restrict__ ws) {
  __shared__ unsigned short lhs[32 * 260];
  const int c = blockIdx.x;
  const int tid = threadIdx.x;
  const int k0 = c * 32;
  unsigned short* cbhi = (unsigned short*)(ws + WS_CBHI);
  unsigned short* cbt  = (unsigned short*)(ws + WS_CBT);
#pragma unroll
  for (int i = 0; i < 8; ++i) {
    int F = tid + i * 256;
    int code = F >> 6, d4 = (F & 63) * 4;
    float4 v = *(const float4*)(cb + (size_t)(k0 + code) * DIMV + d4);
    unsigned short h0 = f2bf(v.x), h1 = f2bf(v.y), h2 = f2bf(v.z), h3 = f2bf(v.w);
    ushort4 hv = {h0, h1, h2, h3};
    *(ushort4*)(cbhi + (size_t)(k0 + code) * DIMV + d4) = hv;
    *(ushort4*)(&lhs[code * 260 + d4]) = hv;
  }
  __syncthreads();
  const int d = tid;
  unsigned short vals[32];
#pragma unroll
  for (int cc = 0; cc < 32; ++cc) vals[cc] = lhs[cc * 260 + d];
  unsigned short* base = cbt + (size_t)c * 8192 + (size_t)d * 32;
#pragma unroll
  for (int j = 0; j < 8; ++j) {
    ushort4 w = {vals[4 * j], vals[4 * j + 1], vals[4 * j + 2], vals[4 * j + 3]};
    *(ushort4*)(base + j * 4) = w;
  }
}

// ================= main v11: wave-specialized producer/consumer pipeline =================
__global__ __launch_bounds__(512, 2)
void vq_main_v11(const float* __restrict__ z, const float* __restrict__ cb,
                 float* __restrict__ out, char* __restrict__ ws) {
  __shared__ __align__(16) char sm[SMEM_BYTES];

  if (blockIdx.x & 1) __builtin_amdgcn_s_sleep(80);

  const int tid  = threadIdx.x;
  const int wave = tid >> 6;          // 0..7
  const int lane = tid & 63;
  const int quad = lane >> 4;
  const int n    = lane & 15;
  const int r0   = blockIdx.x * RT;
  const char* cbhi_b = ws + WS_CBHI;
  const char* cbt_b  = ws + WS_CBT;
  float* wsA = (float*)(ws + WS_ACC);

  const bool isG1 = (wave < 2);
  const bool isG2 = (wave == 2 || wave == 3);
  const int  gw   = wave;             // G1 row-half (0/1)
  const int  g2   = wave - 2;         // G2 dim-half (0/1)
  const int  cw   = wave - 4;         // C-wave 0..3
  const int  crow = (quad & 1) * 16 + n;       // C: row 0..31
  const int  cq   = cw * 2 + (quad >> 1);      // C: code-quad 0..7

  // ---- prologue: z fp32 -> persistent bf16 LDS tile ----
  {
    unsigned short* zt = (unsigned short*)(sm + ZT_OFF);
#pragma unroll
    for (int i = 0; i < 4; ++i) {
      int F = tid + i * 512;                   // 0..2047
      int row = F >> 6, d4 = (F & 63) * 4;
      float4 v = *(const float4*)(z + (size_t)(r0 + row) * DIMV + d4);
      ushort4 hv = {f2bf(v.x), f2bf(v.y), f2bf(v.z), f2bf(v.w)};
      *(ushort4*)(&zt[row * ZT_ROW + d4]) = hv;
    }
  }
  __syncthreads();
  // ---- prologue staging: CBH[0] (16 blocks, 2 per wave) ----
#pragma unroll
  for (int i = 0; i < 2; ++i) {
    int b = wave * 2 + i;
    dma16(cbhi_b + (size_t)(2 * b) * 512 + (size_t)lane * 16, sm + CBH0_OFF + b * BSTRIDE);
  }
  __syncthreads();   // drain CBH[0]

  // ---- per-role persistent state ----
  float4v acc2[16];                           // G2 only
#pragma unroll
  for (int t = 0; t < 16; ++t) acc2[t] = (float4v){0.f, 0.f, 0.f, 0.f};
  uint64_t K0 = 0, K1 = 0, K2 = 0, K3 = 0;    // C only: packed top-4 (key|~idx)
  float skl = 0.f, tkl = 0.f, s2l = 0.f;      // C only
  uint32_t bits4[4];                          // C: SEG1 -> SEG2
  uint32_t idxA = (uint32_t)(r0 + crow) * (uint32_t)N_CODES + (uint32_t)(cq * 4);

  const char* abase = sm + ZT_OFF + (size_t)(gw * 16 + n) * (ZT_ROW * 2) + quad * 16;

#define G2_BODY(cm, pbuf)                                                        \
  {                                                                              \
    const char* pr = sm + P0_OFF + (pbuf) * P_BUF_SZ;                            \
    short8 pa0 = *(const short8*)(pr + n * P_ROW + quad * 16);                   \
    short8 pa1 = *(const short8*)(pr + (16 + n) * P_ROW + quad * 16);            \
    const char* gcb = cbt_b + (size_t)(cm) * 16384 +                             \
                      (size_t)(g2 * 128 + n) * 64 + (size_t)(quad * 16);         \
    _Pragma("unroll")                                                            \
    for (int t = 0; t < 8; ++t) {                                                \
      short8 bbv = *(const short8*)(gcb + t * 1024);                             \
      acc2[t * 2 + 0] = __builtin_amdgcn_mfma_f32_16x16x32_bf16(pa0, bbv, acc2[t * 2 + 0], 0, 0, 0); \
      acc2[t * 2 + 1] = __builtin_amdgcn_mfma_f32_16x16x32_bf16(pa1, bbv, acc2[t * 2 + 1], 0, 0, 0); \
    }                                                                            \
  }

  for (int c = 0; c < NIT3; ++c) {
    const int par = c & 1;

    // ================= SEG1 =================
    if (isG1) {
      // logits for rows gw*16..+15, all 32 codes of chunk c -> ACC
      const char* cbhb = sm + (par ? CBH1_OFF : CBH0_OFF);
#pragma unroll
      for (int nt2 = 0; nt2 < 2; ++nt2) {
        const int kc = nt2 * 16 + n;
        const char* bbase = cbhb + (kc >> 1) * BSTRIDE + (kc & 1) * 512 + quad * 16;
        float4v e0 = (float4v){0.f, 0.f, 0.f, 0.f};
        float4v e1 = (float4v){0.f, 0.f, 0.f, 0.f};
#pragma unroll
        for (int ks = 0; ks < 4; ++ks) {
          short8 za  = *(const short8*)(abase + (2 * ks) * 64);
          short8 zb8 = *(const short8*)(abase + (2 * ks + 1) * 64);
          short8 ba  = *(const short8*)(bbase + (2 * ks) * 64);
          short8 bb2 = *(const short8*)(bbase + (2 * ks + 1) * 64);
          e0 = __builtin_amdgcn_mfma_f32_16x16x32_bf16(za, ba, e0, 0, 0, 0);
          e1 = __builtin_amdgcn_mfma_f32_16x16x32_bf16(zb8, bb2, e1, 0, 0, 0);
        }
        float4v a1 = e0 + e1;
        float4 st = {a1[0], a1[1], a1[2], a1[3]};
        *(float4*)(sm + ACC_OFF + (size_t)(nt2 * 16 + n) * ACC_ROW
                   + (size_t)((gw * 16 + quad * 4) * 4)) = st;
      }
    } else if (isG2) {
      if (c > 0) { G2_BODY(c - 1, (c - 1) & 1) }
    } else {
      // C: threefry for chunk c (counter-only, no deps)
#pragma unroll
      for (int j = 0; j < 4; ++j)
        bits4[j] = threefry_bits(idxA + (uint32_t)j);
    }
    __syncthreads();   // BAR1: ACC(c) ready; P(c-1) consumed by G2

    // ================= SEG2 =================
    if (c + 1 < NIT3 && wave < 4) {
      const size_t kb = (size_t)((c + 1) * CK3);
      char* dst = sm + (par ? CBH0_OFF : CBH1_OFF);
#pragma unroll
      for (int i = 0; i < 4; ++i) {
        int b = wave * 4 + i;
        dma16(cbhi_b + (kb + 2 * b) * 512 + (size_t)lane * 16, dst + b * BSTRIDE);
      }
    }
    if (wave >= 4) {
      // C: float part for chunk c (bit-identical values to v5)
      const char* accp = sm + ACC_OFF;
      float lv[4];
#pragma unroll
      for (int j = 0; j < 4; ++j)
        lv[j] = *(const float*)(accp + (size_t)(cq * 4 + j) * ACC_ROW + (size_t)(crow * 4));
      char* pw = sm + P0_OFF + par * P_BUF_SZ;
      unsigned short ph4[4];
#pragma unroll
      for (int j = 0; j < 4; ++j) {
        float l = lv[j];
        uint32_t bits = bits4[j];
        float u = __uint_as_float((bits >> 9) | 0x3f800000u) - 1.0f;   // [0,1)
        float t = -0.69314718056f * __log2f(fmaxf(u, 1.17549435e-38f));
        t = fmaxf(t, 1.0e-10f);              // guard t->0 => inf p
        float e = __expf(l);
        skl += e;
        tkl = fmaf(e, l, tkl);
        int cg = c * CK3 + cq * 4 + j;
        uint64_t key = ((uint64_t)fkey(l) << 32) | (uint32_t)(~(uint32_t)cg);
        bool b1 = key > K0, b2 = key > K1, b3 = key > K2, b4 = key > K3;
        K3 = b3 ? K2 : (b4 ? key : K3);
        K2 = b2 ? K1 : (b3 ? key : K2);
        K1 = b1 ? K0 : (b2 ? key : K1);
        K0 = b1 ? key : K0;
        float p = e * __builtin_amdgcn_rcpf(t) * 6.1442123533282097e-06f;
        ph4[j] = f2bf(p);
        s2l += bf2f(ph4[j]);                 // denominator from rounded P
      }
      ushort4 pv = {ph4[0], ph4[1], ph4[2], ph4[3]};
      *(ushort4*)(pw + crow * P_ROW + cq * 8) = pv;
      idxA += (uint32_t)CK3;
    }
    __syncthreads();   // BAR2: P(c) ready; DMA(c+1) drained
  }
  // final G2 for the last chunk
  if (isG2) { G2_BODY(NIT3 - 1, (NIT3 - 1) & 1) }
#undef G2_BODY

  // ================= epilogue =================
  if (wave >= 4) {
    // stats: partner lane^32 covers the wave's other code-quad (same row)
    skl += __shfl_xor(skl, 32);
    tkl += __shfl_xor(tkl, 32);
    s2l += __shfl_xor(s2l, 32);
    if (quad < 2) {
      *(float*)(sm + SKL_OFF + cw * 128 + crow * 4) = skl;
      *(float*)(sm + TKL_OFF + cw * 128 + crow * 4) = tkl;
      *(float*)(sm + S2B_OFF + cw * 128 + crow * 4) = s2l;
    }
    // cand dump: 4 decoded (v, idx) entries; [row][8 slots x 32B]
    char* cbase = sm + CAND_OFF + (size_t)crow * 256 + (size_t)cq * 32;
    uint64_t Ks[4] = {K0, K1, K2, K3};
#pragma unroll
    for (int k = 0; k < 4; ++k) {
      float v = fkey_inv((uint32_t)(Ks[k] >> 32));
      int idx = (int)(~(uint32_t)Ks[k]);
      *(float*)(cbase + k * 8) = v;
      *(int*)(cbase + k * 8 + 4) = idx;
    }
  }
  __syncthreads();                           // E1

  // KL per row (one lane per row)
  if (tid < 32) {
    int r = tid;
    const float* sklb = (const float*)(sm + SKL_OFF);
    const float* tklb = (const float*)(sm + TKL_OFF);
    float S = (sklb[r] + sklb[32 + r]) + (sklb[64 + r] + sklb[96 + r]);
    float T = (tklb[r] + tklb[32 + r]) + (tklb[64 + r] + tklb[96 + r]);
    float klr = T / S - __logf(S) + 9.010913347279288f;   // ln(8192)
#pragma unroll
    for (int m = 1; m <= 16; m <<= 1) klr += __shfl_xor(klr, m);
    if (r == 0) atomicAdd(&wsA[0], klr);
  }

  // codes: top-8 by bf16 logit from 32 candidates, fp64 refine; 2 lanes/row
  if (tid < 64) {
    int r = tid >> 1, h = tid & 1;
    const char* cbase = sm + CAND_OFF + r * 256 + h * 128;   // 16 entries x 8B
    float bv[8]; int bi8[8];
#pragma unroll
    for (int k = 0; k < 8; ++k) { bv[k] = -INFINITY; bi8[k] = 0x7fffffff; }
    for (int s = 0; s < 16; ++s) {
      float v = *(const float*)(cbase + s * 8);
      int  id = *(const int*)(cbase + s * 8 + 4);
      if ((v > bv[7]) || (v == bv[7] && id < bi8[7])) {
        float cv = v; int ci = id;
#pragma unroll
        for (int k = 0; k < 8; ++k) {
          bool sw = (cv > bv[k]) || (cv == bv[k] && ci < bi8[k]);
          float tv = bv[k]; int ti = bi8[k];
          if (sw) { bv[k] = cv; bi8[k] = ci; cv = tv; ci = ti; }
        }
      }
    }
    // merge partner half's top-8
    float ovv[8]; int ovi[8];
#pragma unroll
    for (int k = 0; k < 8; ++k) {
      ovv[k] = __shfl_xor(bv[k], 1);
      ovi[k] = __shfl_xor(bi8[k], 1);
    }
#pragma unroll
    for (int kk = 0; kk < 8; ++kk) {
      float cv = ovv[kk]; int ci = ovi[kk];
      if ((cv > bv[7]) || (cv == bv[7] && ci < bi8[7])) {
#pragma unroll
        for (int k = 0; k < 8; ++k) {
          bool sw = (cv > bv[k]) || (cv == bv[k] && ci < bi8[k]);
          float tv = bv[k]; int ti = bi8[k];
          if (sw) { bv[k] = cv; bi8[k] = ci; cv = tv; ci = ti; }
        }
      }
    }
    // fp64 refine 4 candidates per lane (lane h takes entries h*4..h*4+3)
    const float* zp = z + (size_t)(r0 + r) * DIMV;
    double best = -1.0e300;
    int bidx = 0x7fffffff;
#pragma unroll
    for (int k = 0; k < 4; ++k) {
      int cidx = bi8[h * 4 + k];
      const float* cp = cb + (size_t)cidx * DIMV;
      double d = 0.0;
      for (int dd = 0; dd < DIMV; dd += 4) {
        float4 zv = *(const float4*)(zp + dd);
        float4 xv = *(const float4*)(cp + dd);
        d += (double)zv.x * xv.x + (double)zv.y * xv.y +
             (double)zv.z * xv.z + (double)zv.w * xv.w;
      }
      if (d > best || (d == best && cidx < bidx)) { best = d; bidx = cidx; }
    }
    double obest = __shfl_xor(best, 1);
    int    obidx = __shfl_xor(bidx, 1);
    bool take = (obest > best) || (obest == best && obidx < bidx);
    int finali = take ? obidx : bidx;
    if (h == 0) out[OUT_CODE + (size_t)(r0 + r)] = (float)finali;
  }

  // z_q_st + commit partial: G2-waves own all 256 dims (128 each)
  if (isG2) {
    float invm0[4], invm1[4];
    {
      const float* s2b = (const float*)(sm + S2B_OFF);
#pragma unroll
      for (int e = 0; e < 4; ++e) {
        int ra = quad * 4 + e, rb = 16 + quad * 4 + e;
        float Sa = (s2b[ra] + s2b[32 + ra]) + (s2b[64 + ra] + s2b[96 + ra]);
        float Sb = (s2b[rb] + s2b[32 + rb]) + (s2b[64 + rb] + s2b[96 + rb]);
        invm0[e] = 1.0f / Sa;
        invm1[e] = 1.0f / Sb;
      }
    }
    float cpart = 0.f;
#pragma unroll
    for (int t = 0; t < 8; ++t) {
      int dim = g2 * 128 + t * 16 + n;
#pragma unroll
      for (int ms = 0; ms < 2; ++ms) {
        float4v a = acc2[t * 2 + ms];
#pragma unroll
        for (int e = 0; e < 4; ++e) {
          int row = ms * 16 + quad * 4 + e;
          float q = a[e] * (ms ? invm1[e] : invm0[e]);
          float zv = z[(size_t)(r0 + row) * DIMV + dim];
          float err = q - zv;
          cpart += err * err;
          out[(size_t)(r0 + row) * DIMV + dim] = zv + err;
        }
      }
    }
#pragma unroll
    for (int m = 1; m <= 32; m <<= 1) cpart += __shfl_xor(cpart, m);
    if (lane == 0) atomicAdd(&wsA[1], cpart);
  }
}

// ================= fallback v1 (fp32 VALU, needs only 8B ws) =================
#define ZSTRIDE  260
#define CSTRIDE  260
#define PSTRIDE  36
#define RSTRIDE  17

__global__ __launch_bounds__(256, 2)
void vq_main_v1(const float* __restrict__ z, const float* __restrict__ cb,
                float* __restrict__ out, float* __restrict__ ws_acc) {
  __shared__ float zt[RT * ZSTRIDE];
  __shared__ float cbt[CK * CSTRIDE];
  __shared__ float ptile[RT * PSTRIDE];
  __shared__ float redb[RT * RSTRIDE];
  __shared__ float m2s[RT], s2s[RT], scls[RT];

  const int tid = threadIdx.x;
  const int r0  = blockIdx.x * RT;
#pragma unroll
  for (int p = 0; p < 8; ++p) {
    int q = tid + p * 256;
    int i = q >> 6, c4 = (q & 63) * 4;
    *(float4*)(&zt[i * ZSTRIDE + c4]) = *(const float4*)(z + (size_t)(r0 + i) * DIMV + c4);
  }
  if (tid < RT) { m2s[tid] = -INFINITY; s2s[tid] = 0.f; scls[tid] = 0.f; }
  const int tr = tid & 15, tk = tid >> 4, rowg = tid >> 6;
  const int d4 = (tid & 63) * 4;
  float c_m[2][2], c_s[2][2], c_t[2][2];
  int   c_i[2][2];
#pragma unroll
  for (int a = 0; a < 2; ++a)
#pragma unroll
    for (int b = 0; b < 2; ++b) { c_m[a][b] = -INFINITY; c_s[a][b] = 0.f; c_t[a][b] = 0.f; c_i[a][b] = 0; }
  float acc2[8][4];
#pragma unroll
  for (int j = 0; j < 8; ++j)
#pragma unroll
    for (int e = 0; e < 4; ++e) acc2[j][e] = 0.f;
  __syncthreads();
  for (int c = 0; c < NCHUNK; ++c) {
    const int k0 = c * CK;
#pragma unroll
    for (int p = 0; p < 8; ++p) {
      int q = tid + p * 256;
      int i = q >> 6, c4 = (q & 63) * 4;
      *(float4*)(&cbt[i * CSTRIDE + c4]) = *(const float4*)(cb + (size_t)(k0 + i) * DIMV + c4);
    }
    __syncthreads();
    float l00 = 0.f, l01 = 0.f, l10 = 0.f, l11 = 0.f;
    {
      const float* zp0 = &zt[tr * ZSTRIDE];
      const float* zp1 = &zt[(tr + 16) * ZSTRIDE];
      const float* bp0 = &cbt[tk * CSTRIDE];
      const float* bp1 = &cbt[(tk + 16) * CSTRIDE];
#pragma unroll 4
      for (int d = 0; d < DIMV; d += 4) {
        float4 a0 = *(const float4*)(zp0 + d);
        float4 a1 = *(const float4*)(zp1 + d);
        float4 b0 = *(const float4*)(bp0 + d);
        float4 b1 = *(const float4*)(bp1 + d);
        l00 += a0.x*b0.x + a0.y*b0.y + a0.z*b0.z + a0.w*b0.w;
        l01 += a0.x*b1.x + a0.y*b1.y + a0.z*b1.z + a0.w*b1.w;
        l10 += a1.x*b0.x + a1.y*b0.y + a1.z*b0.z + a1.w*b0.w;
        l11 += a1.x*b1.x + a1.y*b1.y + a1.z*b1.z + a1.w*b1.w;
      }
    }
    float lv2[2][2] = {{l00, l01}, {l10, l11}};
    float a2[2][2];
#pragma unroll
    for (int a = 0; a < 2; ++a) {
      int grow = r0 + tr + a * 16;
#pragma unroll
      for (int b = 0; b < 2; ++b) {
        int gk = k0 + tk + b * 16;
        float g  = gumbel_at_v1((uint32_t)grow * (uint32_t)N_CODES + (uint32_t)gk);
        float lv = lv2[a][b];
        a2[a][b] = lv + g;
        if (lv > c_m[a][b]) {
          float sc = expf(c_m[a][b] - lv);
          c_s[a][b] = c_s[a][b] * sc + 1.0f;
          c_t[a][b] = c_t[a][b] * sc + lv;
          c_m[a][b] = lv;
          c_i[a][b] = gk;
        } else {
          float e = expf(lv - c_m[a][b]);
          c_s[a][b] += e;
          c_t[a][b] += e * lv;
        }
      }
    }
    redb[tr * RSTRIDE + tk]        = fmaxf(a2[0][0], a2[0][1]);
    redb[(tr + 16) * RSTRIDE + tk] = fmaxf(a2[1][0], a2[1][1]);
    __syncthreads();
    if (tid < RT) {
      float cm = -INFINITY;
#pragma unroll
      for (int j = 0; j < 16; ++j) cm = fmaxf(cm, redb[tid * RSTRIDE + j]);
      float m2n = fmaxf(m2s[tid], cm);
      scls[tid] = expf(m2s[tid] - m2n);
      m2s[tid]  = m2n;
    }
    __syncthreads();
#pragma unroll
    for (int a = 0; a < 2; ++a) {
      int row = tr + a * 16;
      float m2r = m2s[row];
      float p0 = expf(a2[a][0] - m2r);
      float p1 = expf(a2[a][1] - m2r);
      ptile[row * PSTRIDE + tk]      = p0;
      ptile[row * PSTRIDE + tk + 16] = p1;
      redb[row * RSTRIDE + tk] = p0 + p1;
    }
    __syncthreads();
    if (tid < RT) {
      float ss = 0.f;
#pragma unroll
      for (int j = 0; j < 16; ++j) ss += redb[tid * RSTRIDE + j];
      s2s[tid] = s2s[tid] * scls[tid] + ss;
    }
#pragma unroll
    for (int j = 0; j < 8; ++j) {
      float sc = scls[rowg * 8 + j];
      acc2[j][0] *= sc; acc2[j][1] *= sc; acc2[j][2] *= sc; acc2[j][3] *= sc;
    }
    for (int k4 = 0; k4 < CK; k4 += 4) {
      float4 cb0 = *(const float4*)(&cbt[(k4 + 0) * CSTRIDE + d4]);
      float4 cb1v = *(const float4*)(&cbt[(k4 + 1) * CSTRIDE + d4]);
      float4 cb2 = *(const float4*)(&cbt[(k4 + 2) * CSTRIDE + d4]);
      float4 cb3 = *(const float4*)(&cbt[(k4 + 3) * CSTRIDE + d4]);
#pragma unroll
      for (int j = 0; j < 8; ++j) {
        float4 p4 = *(const float4*)(&ptile[(rowg * 8 + j) * PSTRIDE + k4]);
        acc2[j][0] += p4.x*cb0.x + p4.y*cb1v.x + p4.z*cb2.x + p4.w*cb3.x;
        acc2[j][1] += p4.x*cb0.y + p4.y*cb1v.y + p4.z*cb2.y + p4.w*cb3.y;
        acc2[j][2] += p4.x*cb0.z + p4.y*cb1v.z + p4.z*cb2.z + p4.w*cb3.z;
        acc2[j][3] += p4.x*cb0.w + p4.y*cb1v.w + p4.z*cb2.w + p4.w*cb3.w;
      }
    }
    __syncthreads();
  }
  float* kbuf = cbt;
#pragma unroll
  for (int a = 0; a < 2; ++a) {
    float m0 = c_m[a][0], m1v = c_m[a][1];
    float m, s, t; int bi;
    if (m0 >= m1v) {
      float e = expf(m1v - m0);
      m = m0; s = c_s[a][0] + c_s[a][1] * e; t = c_t[a][0] + c_t[a][1] * e;
    } else {
      float e = expf(m0 - m1v);
      m = m1v; s = c_s[a][0] * e + c_s[a][1]; t = c_t[a][0] * e + c_t[a][1];
    }
    if (m0 > m1v)      bi = c_i[a][0];
    else if (m1v > m0) bi = c_i[a][1];
    else               bi = min(c_i[a][0], c_i[a][1]);
    int row = tr + a * 16;
    kbuf[row * 65 + tk * 4 + 0] = m;
    kbuf[row * 65 + tk * 4 + 1] = s;
    kbuf[row * 65 + tk * 4 + 2] = t;
    kbuf[row * 65 + tk * 4 + 3] = (float)bi;
  }
  __syncthreads();
  if (tid < RT) {
    int r = tid;
    float M = -INFINITY, S = 0.f, T = 0.f, BM = -INFINITY;
    int BI = 0x7fffffff;
    for (int j = 0; j < 16; ++j) {
      float m  = kbuf[r * 65 + j * 4 + 0];
      float s  = kbuf[r * 65 + j * 4 + 1];
      float t  = kbuf[r * 65 + j * 4 + 2];
      int   bi = (int)kbuf[r * 65 + j * 4 + 3];
      if (m <= M) {
        float e = expf(m - M);
        S += s * e; T += t * e;
      } else {
        float e = expf(M - m);
        S = S * e + s; T = T * e + t; M = m;
      }
      if (m > BM || (m == BM && bi < BI)) { BM = m; BI = bi; }
    }
    float kl = logf((float)N_CODES) + T / S - M - logf(S);
    atomicAdd(&ws_acc[0], kl);
    out[OUT_CODE + (size_t)(r0 + r)] = (float)BI;
  }
  float cpart = 0.f;
#pragma unroll
  for (int j = 0; j < 8; ++j) {
    int row  = rowg * 8 + j;
    int grow = r0 + row;
    float inv = 1.0f / s2s[row];
    float4 zv = *(const float4*)(&zt[row * ZSTRIDE + d4]);
    float q0 = acc2[j][0] * inv, q1 = acc2[j][1] * inv;
    float q2 = acc2[j][2] * inv, q3 = acc2[j][3] * inv;
    float e0 = q0 - zv.x, e1 = q1 - zv.y, e2 = q2 - zv.z, e3 = q3 - zv.w;
    cpart += e0*e0 + e1*e1 + e2*e2 + e3*e3;
    float4 o;
    o.x = zv.x + e0; o.y = zv.y + e1; o.z = zv.z + e2; o.w = zv.w + e3;
    *(float4*)(&out[(size_t)grow * DIMV + d4]) = o;
  }
#pragma unroll
  for (int off = 32; off > 0; off >>= 1) cpart += __shfl_down(cpart, off, 64);
  __syncthreads();
  if ((tid & 63) == 0) redb[tid >> 6] = cpart;
  __syncthreads();
  if (tid == 0) {
    float cs = redb[0] + redb[1] + redb[2] + redb[3];
    atomicAdd(&ws_acc[1], cs);
  }
}

__global__ void vq_finalize(const float* __restrict__ ws_acc, float* __restrict__ out) {
  if (threadIdx.x == 0 && blockIdx.x == 0) {
    float kl = 0.01f * (ws_acc[0] / (float)N_ROWS);
    float cm = 0.25f * (ws_acc[1] / (float)OUT_ZQ_N);
    out[OUT_LOSS] = cm + kl;
  }
}

extern "C" void kernel_launch(void* const* d_in, const int* in_sizes, int n_in,
                              void* d_out, int out_size, void* d_ws, size_t ws_size,
                              hipStream_t stream) {
  (void)in_sizes; (void)n_in; (void)out_size;
  const float* z  = (const float*)d_in[0];
  const float* cb = (const float*)d_in[1];
  float* out = (float*)d_out;
  if (ws_size >= (size_t)WS_NEED) {
    char* ws = (char*)d_ws;
    hipMemsetAsync(ws + WS_ACC, 0, 8, stream);
    vq_prep<<<256, 256, 0, stream>>>(cb, ws);
    vq_main_v11<<<N_ROWS / RT, 512, 0, stream>>>(z, cb, out, ws);
    vq_finalize<<<1, 64, 0, stream>>>((const float*)(ws + WS_ACC), out);
  } else {
    float* ws = (float*)d_ws;
    hipMemsetAsync(ws, 0, 8, stream);
    vq_main_v1<<<N_ROWS / RT, 256, 0, stream>>>(z, cb, out, ws);
    vq_finalize<<<1, 64, 0, stream>>>(ws, out);
  }
}